// Round 7
// baseline (143.075 us; speedup 1.0000x reference)
//
#include <hip/hip_runtime.h>

// A8W8 GEMM, fp16-saturating output. C = (a_i8 @ b_i8^T) * arow * acol.
// Pass 1: pack int32 -> int8. Pass 2: 256x256 tile, BKB=64, 8 waves,
// 4-slot circular LDS pipeline with ONE barrier per K-step and full
// register read-ahead: iter j MFMAs tile j from regs (read iter j-1),
// ds_reads tile j+1, gload-stages tile j+3, vmcnt(4) keeps newest tile
// in flight across the raw barrier. R3's verified staging swizzle.

constexpr int MD = 4096, ND = 4096, KD = 4096;
constexpr int BM = 256, BN = 256, BKB = 64;  // K-step bytes (= 64 i8 = MFMA K)
constexpr int NT = KD / BKB;                 // 64 K-steps
constexpr int TB = BM * BKB;                 // 16 KiB per matrix per slot

using i32x4 = __attribute__((ext_vector_type(4))) int;

#define VMCNT(n) asm volatile("s_waitcnt vmcnt(" #n ")" ::: "memory")
#define BAR() __builtin_amdgcn_s_barrier()

// ---------------- pack: int32 (one value per elem) -> int8 ----------------
__global__ __launch_bounds__(256) void pack_i8(const int* __restrict__ in,
                                               char* __restrict__ out) {
  const size_t t = (size_t)blockIdx.x * 256 + threadIdx.x;
  const int4* p = (const int4*)in + t * 4;
  int4 v0 = p[0], v1 = p[1], v2 = p[2], v3 = p[3];
  int4 o;
  o.x = v0.x | (v0.y << 8) | (v0.z << 16) | (v0.w << 24);
  o.y = v1.x | (v1.y << 8) | (v1.z << 16) | (v1.w << 24);
  o.z = v2.x | (v2.y << 8) | (v2.z << 16) | (v2.w << 24);
  o.w = v3.x | (v3.y << 8) | (v3.z << 16) | (v3.w << 24);
  ((int4*)out)[t] = o;
}

// ---------------- GEMM ----------------------------------------------------
__device__ inline void load16_lds(const char* g, char* l) {
  __builtin_amdgcn_global_load_lds(
      (const __attribute__((address_space(1))) void*)g,
      (__attribute__((address_space(3))) void*)l, 16, 0, 0);
}

// reference fp16 cast, saturating (all values >= 0; |inf-finite|=inf passes)
__device__ inline float f16_sat(float v) {
  v = fminf(v, 65504.0f);
  return (float)(_Float16)v;
}

__global__ __launch_bounds__(512, 2) void gemm_i8w8(
    const char* __restrict__ A, const char* __restrict__ B,
    const float* __restrict__ arow, const float* __restrict__ acol,
    float* __restrict__ out) {
  __shared__ char sA[4][TB];  // 64 KiB
  __shared__ char sB[4][TB];  // 64 KiB

  const int tid = threadIdx.x;
  const int wv = tid >> 6;
  const int lane = tid & 63;

  // XCD-aware bijective swizzle (nwg = 256, divisible by 8)
  const int bid = blockIdx.x;
  const int wg = (bid & 7) * 32 + (bid >> 3);
  const int brow = wg >> 4;
  const int bcol = wg & 15;

  // 2(M) x 4(N) wave grid; per-wave output 128 x 64
  const int wrow = (wv >> 2) * 128;
  const int wcol = (wv & 3) * 64;

  i32x4 acc[8][4] = {};

  // ---- staging (R3-verified): per K-step each matrix = 1024 chunks of
  // 16B; thread owns chunks c0=tid, c1=tid+512. LDS dest LINEAR (gload:
  // wave base + lane*16). Source slot pre-swizzled (rule 21):
  // LDS[row][s] = G[row][s ^ ((row>>1)&3)], row = c>>2, s = c&3.
  const int c0 = tid, c1 = tid + 512;
  const int sg0 = ((c0 & 3) ^ ((c0 >> 3) & 3)) * 16;
  const int sg1 = ((c1 & 3) ^ ((c1 >> 3) & 3)) * 16;
  const size_t aG0 = (size_t)(brow * BM + (c0 >> 2)) * KD + sg0;
  const size_t aG1 = (size_t)(brow * BM + (c1 >> 2)) * KD + sg1;
  const size_t bG0 = (size_t)(bcol * BN + (c0 >> 2)) * KD + sg0;
  const size_t bG1 = (size_t)(bcol * BN + (c1 >> 2)) * KD + sg1;
  const int ldsOff0 = wv * 1024;         // chunks [wv*64, wv*64+64)
  const int ldsOff1 = 8192 + wv * 1024;  // chunks [512+wv*64, ...)

  auto issue_tile = [&](int s, int t) {  // 4 gloads, slot s <- K-step t
    const size_t ko = (size_t)t * BKB;
    load16_lds(A + aG0 + ko, sA[s] + ldsOff0);
    load16_lds(A + aG1 + ko, sA[s] + ldsOff1);
    load16_lds(B + bG0 + ko, sB[s] + ldsOff0);
    load16_lds(B + bG1 + ko, sB[s] + ldsOff1);
  };

  // ---- fragment reads (R3-verified, 0 bank conflicts): lane l -> row
  // base+(l&15), G-slot (l>>4); LDS slot = (l>>4) ^ ((row>>1)&3).
  const int r = lane & 15;
  const int sl = ((lane >> 4) ^ ((r >> 1) & 3)) * 16;
  const int aBase = (wrow + r) * BKB;  // + m*1024 per frag
  const int bBase = (wcol + r) * BKB;  // + n*1024 per frag

  i32x4 afA[8], afB[8], bf[4];

  // ---- one K-step body, ONE barrier. MFMAs tile j from afC (read last
  // iter); reads afN <- tile j+1; stages tile j+3; vmcnt(4) keeps the
  // just-issued tile in flight across the barrier (retires tile j+2,
  // which is read next iter).
  auto body = [&](int j, int sc, int sn, int ss, i32x4(&afC)[8],
                  i32x4(&afN)[8]) {
    const char* pb = sB[sc] + bBase;
#pragma unroll
    for (int n = 0; n < 4; ++n)
      bf[n] = *(const i32x4*)(pb + n * 1024 + sl);
    if (j + 3 < NT) issue_tile(ss, j + 3);
    if (j + 1 < NT) {
      const char* pan = sA[sn] + aBase;
#pragma unroll
      for (int m = 0; m < 8; ++m)
        afN[m] = *(const i32x4*)(pan + m * 1024 + sl);
    }
    __builtin_amdgcn_s_setprio(1);
#pragma unroll
    for (int n = 0; n < 4; ++n)  // n-outer: first MFMAs wait only bf[0]
#pragma unroll
      for (int m = 0; m < 8; ++m)
        acc[m][n] = __builtin_amdgcn_mfma_i32_16x16x64_i8(afC[m], bf[n],
                                                          acc[m][n], 0, 0, 0);
    __builtin_amdgcn_s_setprio(0);
    if (j <= NT - 4) {
      VMCNT(4);  // retire tile j+2 (read next iter); keep tile j+3 in flight
    } else {
      VMCNT(0);  // tail drain
    }
    BAR();
  };

  // ---- prologue: 3 tiles in flight; retire tiles 0,1; pre-read af(tile 0)
  issue_tile(0, 0);
  issue_tile(1, 1);
  issue_tile(2, 2);
  VMCNT(4);  // tiles 0,1 landed; tile 2 (4 loads) in flight
  BAR();
  {
    const char* pa0 = sA[0] + aBase;
#pragma unroll
    for (int m = 0; m < 8; ++m)
      afA[m] = *(const i32x4*)(pa0 + m * 1024 + sl);
  }

  for (int j4 = 0; j4 < NT; j4 += 4) {  // slots cycle 0,1,2,3; af ping-pong
    body(j4 + 0, 0, 1, 3, afA, afB);
    body(j4 + 1, 1, 2, 0, afB, afA);
    body(j4 + 2, 2, 3, 1, afA, afB);
    body(j4 + 3, 3, 0, 2, afB, afA);
  }

  // ---- epilogue: C/D map col=lane&15, row=(lane>>4)*4+reg (16x16 shapes)
  const int orow0 = brow * BM + wrow + ((lane >> 4) << 2);
  const int ocol0 = bcol * BN + wcol + (lane & 15);
#pragma unroll
  for (int m = 0; m < 8; ++m) {
    const int rb = orow0 + m * 16;
    const float ar0 = arow[rb + 0], ar1 = arow[rb + 1];
    const float ar2 = arow[rb + 2], ar3 = arow[rb + 3];
#pragma unroll
    for (int n = 0; n < 4; ++n) {
      const int col = ocol0 + n * 16;
      const float ac = acol[col];
      out[(size_t)(rb + 0) * ND + col] = f16_sat((float)acc[m][n][0] * (ar0 * ac));
      out[(size_t)(rb + 1) * ND + col] = f16_sat((float)acc[m][n][1] * (ar1 * ac));
      out[(size_t)(rb + 2) * ND + col] = f16_sat((float)acc[m][n][2] * (ar2 * ac));
      out[(size_t)(rb + 3) * ND + col] = f16_sat((float)acc[m][n][3] * (ar3 * ac));
    }
  }
}

extern "C" void kernel_launch(void* const* d_in, const int* in_sizes, int n_in,
                              void* d_out, int out_size, void* d_ws, size_t ws_size,
                              hipStream_t stream) {
  const int* a = (const int*)d_in[0];         // [M,K] int32 (int8 values)
  const int* b = (const int*)d_in[1];         // [N,K] int32 (int8 values)
  const float* arow = (const float*)d_in[2];  // [M,1]
  const float* acol = (const float*)d_in[3];  // [1,N]
  float* out = (float*)d_out;

  char* pa = (char*)d_ws;                    // 16 MiB packed A
  char* pb = pa + (size_t)MD * KD;           // 16 MiB packed B

  const int packBlocks = (int)(((size_t)MD * KD) / (16 * 256));  // 4096
  pack_i8<<<packBlocks, 256, 0, stream>>>(a, pa);
  pack_i8<<<packBlocks, 256, 0, stream>>>(b, pb);

  const int grid = (MD / BM) * (ND / BN);  // 256 blocks, 1 per CU
  gemm_i8w8<<<grid, 512, 0, stream>>>(pa, pb, arow, acol, out);
}